// Round 1
// baseline (152.374 us; speedup 1.0000x reference)
//
#include <hip/hip_runtime.h>

typedef float f32x4 __attribute__((ext_vector_type(4)));
typedef __bf16 bf16x8 __attribute__((ext_vector_type(8)));

#define SPAT 65536   // t*h*w
#define CH   128
#define NE   8

__device__ __forceinline__ unsigned short f2b(float f) {
    unsigned u = __builtin_bit_cast(unsigned, f);
    unsigned r = u + 0x7FFFu + ((u >> 16) & 1u);
    return (unsigned short)(r >> 16);
}
__device__ __forceinline__ unsigned pk2(float a, float b) {
    return (unsigned)f2b(a) | ((unsigned)f2b(b) << 16);
}

// LDS layout (bytes):
//   XS  [0,      65536) : X tile   [256 tok][128 ch] bf16, 16B-granule XOR swizzle
//   H1  [65536, 131072) : h1 tile  [256 tok][128 o ] bf16, same swizzle
//                         (pre-loop alias: gating scratch)
//   WS  [131072,163840) : weight   [128 o  ][128 c ] bf16, same swizzle
__global__ __launch_bounds__(512, 2)
void moe_fused(const float* __restrict__ x,  const float* __restrict__ gw,
               const float* __restrict__ gb, const float* __restrict__ W1,
               const float* __restrict__ b1, const float* __restrict__ alpha,
               const float* __restrict__ W2, const float* __restrict__ b2,
               float* __restrict__ out)
{
    __shared__ __align__(16) unsigned char smem[163840];
    unsigned char* XS = smem;
    unsigned char* H1 = smem + 65536;
    unsigned char* WS = smem + 131072;

    const int t    = threadIdx.x;
    const int lane = t & 63;
    const int w    = t >> 6;
    const int blk  = blockIdx.x;
    // token block: 256 consecutive spatial positions within one batch image
    const size_t xbase = (size_t)(blk >> 8) * ((size_t)CH * SPAT) + (size_t)((blk & 255) << 8);

    // ---------------- stage X (fp32->bf16, swizzled) + fp32 gating ----------------
    {
        const int m = t & 255, half = t >> 8;
        f32x4 plo = {0.f,0.f,0.f,0.f}, phi = {0.f,0.f,0.f,0.f};
        #pragma unroll
        for (int cc = 0; cc < 8; ++cc) {
            const int c0 = half * 64 + cc * 8;
            float v[8];
            #pragma unroll
            for (int j = 0; j < 8; ++j)
                v[j] = x[xbase + (size_t)(c0 + j) * SPAT + m];
            #pragma unroll
            for (int j = 0; j < 8; ++j) {
                const f32x4 g0 = *(const f32x4*)(gw + (c0 + j) * NE);
                const f32x4 g1 = *(const f32x4*)(gw + (c0 + j) * NE + 4);
                plo += v[j] * g0;
                phi += v[j] * g1;
            }
            uint4 pkv;
            pkv.x = pk2(v[0], v[1]); pkv.y = pk2(v[2], v[3]);
            pkv.z = pk2(v[4], v[5]); pkv.w = pk2(v[6], v[7]);
            const int g = half * 8 + cc;
            *(uint4*)(XS + m * 256 + ((g ^ (m & 7)) * 16)) = pkv;
        }
        float* pl = (float*)H1;                 // [256][8] partial logits
        if (half) {
            #pragma unroll
            for (int e2 = 0; e2 < 4; ++e2) {
                pl[m * 8 + e2]     = plo[e2];
                pl[m * 8 + 4 + e2] = phi[e2];
            }
        }
        __syncthreads();
        if (!half) {
            float lg[8];
            #pragma unroll
            for (int e2 = 0; e2 < 4; ++e2) {
                lg[e2]     = plo[e2] + pl[m * 8 + e2]     + gb[e2];
                lg[4 + e2] = phi[e2] + pl[m * 8 + 4 + e2] + gb[4 + e2];
            }
            int i0 = 0; float v0 = lg[0];
            #pragma unroll
            for (int e2 = 1; e2 < 8; ++e2) if (lg[e2] > v0) { v0 = lg[e2]; i0 = e2; }
            int i1 = 1; float v1 = -3.4e38f;
            #pragma unroll
            for (int e2 = 0; e2 < 8; ++e2) if (e2 != i0 && lg[e2] > v1) { v1 = lg[e2]; i1 = e2; }
            const float d  = expf(v1 - v0);           // <= 1, stable
            const float q0 = 1.f / (1.f + d);
            const float q1 = d   / (1.f + d);
            ((unsigned*)(H1 + 8192))[m] = (unsigned)i0 | ((unsigned)i1 << 8);
            ((float*)(H1 + 9216))[m]  = q0;
            ((float*)(H1 + 10240))[m] = q1;
        }
        __syncthreads();
    }

    // wave tiling: 2 M-groups (64 out-chans) x 4 N-groups (64 tokens)
    const int mg  = w >> 2, ng = w & 3;
    const int col = lane & 15, kq = lane >> 4;

    int sel[4]; float cp0[4], cp1[4];
    #pragma unroll
    for (int nf = 0; nf < 4; ++nf) {
        const int tk = ng * 64 + nf * 16 + col;
        sel[nf] = ((const unsigned*)(H1 + 8192))[tk];
        cp0[nf] = ((const float*)(H1 + 9216))[tk];
        cp1[nf] = ((const float*)(H1 + 10240))[tk];
    }
    // preload X B-frags (immutable all kernel): [nf][kt]
    uint4 xb[4][4];
    #pragma unroll
    for (int nf = 0; nf < 4; ++nf) {
        const int row = ng * 64 + nf * 16 + col;
        #pragma unroll
        for (int kt = 0; kt < 4; ++kt) {
            const int g = kt * 4 + kq;
            xb[nf][kt] = *(const uint4*)(XS + row * 256 + ((g ^ (row & 7)) * 16));
        }
    }

    // prefetch W1[0] into registers (T14: issue early, LDS-write late)
    f32x4 wr[8];
    #pragma unroll
    for (int it = 0; it < 4; ++it) {
        const int chunk = it * 512 + t;
        wr[2*it]   = *(const f32x4*)(W1 + chunk * 8);
        wr[2*it+1] = *(const f32x4*)(W1 + chunk * 8 + 4);
    }

    f32x4 acc[4][4] = {};   // [m-frag][n-frag] persistent output accumulator

    for (int e = 0; e < NE; ++e) {
        __syncthreads();                       // WS safe to overwrite
        // commit layer-1 weights (held in wr) to LDS as bf16, swizzled
        #pragma unroll
        for (int it = 0; it < 4; ++it) {
            const int chunk = it * 512 + t;
            const int o = chunk >> 4, cc = chunk & 15;
            uint4 pkv;
            pkv.x = pk2(wr[2*it][0],   wr[2*it][1]);
            pkv.y = pk2(wr[2*it][2],   wr[2*it][3]);
            pkv.z = pk2(wr[2*it+1][0], wr[2*it+1][1]);
            pkv.w = pk2(wr[2*it+1][2], wr[2*it+1][3]);
            *(uint4*)(WS + o * 256 + ((cc ^ (o & 7)) * 16)) = pkv;
        }
        // prefetch layer-2 weights (latency hides under GEMM1)
        #pragma unroll
        for (int it = 0; it < 4; ++it) {
            const int chunk = it * 512 + t;
            wr[2*it]   = *(const f32x4*)(W2 + e * 16384 + chunk * 8);
            wr[2*it+1] = *(const f32x4*)(W2 + e * 16384 + chunk * 8 + 4);
        }
        __syncthreads();

        // -------- GEMM1: h1[o][tok] = W1[e] . X^T ; bias, PReLU, *ce ; -> H1 --------
        const float alph = alpha[e];
        #pragma unroll
        for (int ml = 0; ml < 4; ++ml) {
            const int mt = mg * 4 + ml;
            const int o  = mt * 16 + col;
            uint4 a1[4];
            #pragma unroll
            for (int kt = 0; kt < 4; ++kt) {
                const int g = kt * 4 + kq;
                a1[kt] = *(const uint4*)(WS + o * 256 + ((g ^ (o & 7)) * 16));
            }
            f32x4 h[4] = {};
            #pragma unroll
            for (int kt = 0; kt < 4; ++kt)
                #pragma unroll
                for (int nf = 0; nf < 4; ++nf)
                    h[nf] = __builtin_amdgcn_mfma_f32_16x16x32_bf16(
                        __builtin_bit_cast(bf16x8, a1[kt]),
                        __builtin_bit_cast(bf16x8, xb[nf][kt]), h[nf], 0, 0, 0);
            const f32x4 b1v = *(const f32x4*)(b1 + e * CH + mt * 16 + kq * 4);
            #pragma unroll
            for (int nf = 0; nf < 4; ++nf) {
                const float ce = ((sel[nf] & 255) == e) ? cp0[nf]
                               : ((((sel[nf] >> 8) & 255) == e) ? cp1[nf] : 0.f);
                float hv[4];
                #pragma unroll
                for (int i = 0; i < 4; ++i) {
                    float z = h[nf][i] + b1v[i];
                    z = (z > 0.f) ? z : alph * z;
                    hv[i] = z * ce;            // fold combine weight into h1
                }
                const int tok = ng * 64 + nf * 16 + col;
                const int o0  = mt * 16 + kq * 4;
                const int g   = o0 >> 3;
                uint2 pw; pw.x = pk2(hv[0], hv[1]); pw.y = pk2(hv[2], hv[3]);
                *(uint2*)(H1 + tok * 256 + ((g ^ (tok & 7)) * 16) + ((o0 & 4) << 1)) = pw;
            }
        }
        __syncthreads();                       // h1 visible; W1 reads done
        // commit layer-2 weights to LDS
        #pragma unroll
        for (int it = 0; it < 4; ++it) {
            const int chunk = it * 512 + t;
            const int o = chunk >> 4, cc = chunk & 15;
            uint4 pkv;
            pkv.x = pk2(wr[2*it][0],   wr[2*it][1]);
            pkv.y = pk2(wr[2*it][2],   wr[2*it][3]);
            pkv.z = pk2(wr[2*it+1][0], wr[2*it+1][1]);
            pkv.w = pk2(wr[2*it+1][2], wr[2*it+1][3]);
            *(uint4*)(WS + o * 256 + ((cc ^ (o & 7)) * 16)) = pkv;
        }
        // prefetch next expert's layer-1 weights
        if (e < 7) {
            #pragma unroll
            for (int it = 0; it < 4; ++it) {
                const int chunk = it * 512 + t;
                wr[2*it]   = *(const f32x4*)(W1 + (e + 1) * 16384 + chunk * 8);
                wr[2*it+1] = *(const f32x4*)(W1 + (e + 1) * 16384 + chunk * 8 + 4);
            }
        }
        __syncthreads();

        // -------- GEMM2: acc += W2[e] . h1scaled  (ce already folded in) --------
        #pragma unroll
        for (int kt = 0; kt < 4; ++kt) {
            uint4 hb[4];
            #pragma unroll
            for (int nf = 0; nf < 4; ++nf) {
                const int tok = ng * 64 + nf * 16 + col;
                const int g   = kt * 4 + kq;
                hb[nf] = *(const uint4*)(H1 + tok * 256 + ((g ^ (tok & 7)) * 16));
            }
            #pragma unroll
            for (int ml = 0; ml < 4; ++ml) {
                const int o = (mg * 4 + ml) * 16 + col;
                const int g = kt * 4 + kq;
                const uint4 a2 = *(const uint4*)(WS + o * 256 + ((g ^ (o & 7)) * 16));
                #pragma unroll
                for (int nf = 0; nf < 4; ++nf)
                    acc[ml][nf] = __builtin_amdgcn_mfma_f32_16x16x32_bf16(
                        __builtin_bit_cast(bf16x8, a2),
                        __builtin_bit_cast(bf16x8, hb[nf]), acc[ml][nf], 0, 0, 0);
            }
        }
        // + ce * b2[e]
        #pragma unroll
        for (int ml = 0; ml < 4; ++ml) {
            const f32x4 b2v = *(const f32x4*)(b2 + e * CH + (mg * 4 + ml) * 16 + kq * 4);
            #pragma unroll
            for (int nf = 0; nf < 4; ++nf) {
                const float ce = ((sel[nf] & 255) == e) ? cp0[nf]
                               : ((((sel[nf] >> 8) & 255) == e) ? cp1[nf] : 0.f);
                #pragma unroll
                for (int i = 0; i < 4; ++i) acc[ml][nf][i] += ce * b2v[i];
            }
        }
    }

    // ---------------- epilogue: residual + store ----------------
    #pragma unroll
    for (int ml = 0; ml < 4; ++ml) {
        const int p0r = (mg * 4 + ml) * 16 + kq * 4;
        #pragma unroll
        for (int nf = 0; nf < 4; ++nf) {
            const int tok = ng * 64 + nf * 16 + col;
            #pragma unroll
            for (int i = 0; i < 4; ++i) {
                const size_t a = xbase + (size_t)(p0r + i) * SPAT + tok;
                out[a] = acc[ml][nf][i] + x[a];
            }
        }
    }
}

extern "C" void kernel_launch(void* const* d_in, const int* in_sizes, int n_in,
                              void* d_out, int out_size, void* d_ws, size_t ws_size,
                              hipStream_t stream) {
    const float* x  = (const float*)d_in[0];
    const float* gw = (const float*)d_in[1];
    const float* gb = (const float*)d_in[2];
    const float* W1 = (const float*)d_in[3];
    const float* b1 = (const float*)d_in[4];
    const float* al = (const float*)d_in[5];
    const float* W2 = (const float*)d_in[6];
    const float* b2 = (const float*)d_in[7];
    (void)in_sizes; (void)n_in; (void)d_ws; (void)ws_size; (void)out_size;
    float* out = (float*)d_out;
    moe_fused<<<dim3(512), dim3(512), 0, stream>>>(x, gw, gb, W1, b1, al, W2, b2, out);
}

// Round 2
// 128.510 us; speedup vs baseline: 1.1857x; 1.1857x over previous
//
#include <hip/hip_runtime.h>

typedef float f32x4 __attribute__((ext_vector_type(4)));
typedef __bf16 bf16x8 __attribute__((ext_vector_type(8)));

#define SPAT 65536   // t*h*w
#define CH   128
#define NE   8

// LDS layout (bytes)
#define XS_OFF   0        // 65536: X tile [256][128] bf16, swizzled; aliased as H1 after xb preload
#define WA_OFF   65536    // 32768: W1[e] bf16 image
#define WB_OFF   98304    // 32768: W2[e] bf16 image
#define PL_OFF   131072   // 8192 : gating partial logits f32[256][8] (prologue only)
#define SEL_OFF  139264   // 1024 : sel u32[256]
#define Q_OFF    140288   // 2048 : q f32[256][2]
#define B1_OFF   142336   // 4096 : b1 f32[8][128]
#define CB_OFF   146432   // 4096 : combine bf16[256][8]
#define B2T_OFF  150528   // 2048 : b2^T bf16[128][8]
#define AL_OFF   152576   // 32   : alpha f32[8]
#define LDS_BYTES 152608

static __device__ __forceinline__ unsigned short f2b(float f) {
    unsigned u = __builtin_bit_cast(unsigned, f);
    unsigned r = u + 0x7FFFu + ((u >> 16) & 1u);
    return (unsigned short)(r >> 16);
}
static __device__ __forceinline__ unsigned pk2(float a, float b) {
    return (unsigned)f2b(a) | ((unsigned)f2b(b) << 16);
}

typedef const __attribute__((address_space(1))) void* as1cp;
typedef __attribute__((address_space(3))) void* as3p;
static __device__ __forceinline__ void gload16(const void* g, void* l) {
    __builtin_amdgcn_global_load_lds((as1cp)g, (as3p)l, 16, 0, 0);
}

// Pre-convert W1/W2 fp32 -> bf16 images in ws, already in the swizzled LDS
// byte order so the main kernel's global_load_lds is a linear 32KB memcpy.
// Image: ws + mat*262144 + e*32768 + o*256 + ((g ^ (o&7))*16), granule g = 8 ch.
__global__ void conv_w(const float* __restrict__ W1, const float* __restrict__ W2,
                       unsigned char* __restrict__ wimg) {
    const int gid = blockIdx.x * 256 + threadIdx.x;   // 32768 granules
    const int mat = gid >> 14;
    const int e   = (gid >> 11) & 7;
    const int o   = (gid >> 4) & 127;
    const int g   = gid & 15;
    const float* s = (mat ? W2 : W1) + (e * 16384 + o * 128 + g * 8);
    uint4 p;
    p.x = pk2(s[0], s[1]); p.y = pk2(s[2], s[3]);
    p.z = pk2(s[4], s[5]); p.w = pk2(s[6], s[7]);
    *(uint4*)(wimg + mat * 262144 + e * 32768 + o * 256 + ((g ^ (o & 7)) * 16)) = p;
}

__global__ __launch_bounds__(512, 2)
void moe_main(const float* __restrict__ x,  const float* __restrict__ gw,
              const float* __restrict__ gb, const float* __restrict__ b1,
              const float* __restrict__ alpha, const float* __restrict__ b2,
              const unsigned char* __restrict__ wimg, float* __restrict__ out)
{
    __shared__ __align__(16) unsigned char smem[LDS_BYTES];
    const int t = threadIdx.x, lane = t & 63, w = t >> 6, blk = blockIdx.x;
    const size_t xbase = (size_t)(blk >> 8) * (size_t)(CH * SPAT) + (size_t)((blk & 255) << 8);

    // issue expert-0 weight DMA immediately (lands during prologue)
    {
        const int off = w * 1024 + lane * 16, lofs = w * 1024;
        #pragma unroll
        for (int r = 0; r < 4; ++r) {
            gload16(wimg + r * 8192 + off,           smem + WA_OFF + r * 8192 + lofs);
            gload16(wimg + 262144 + r * 8192 + off,  smem + WB_OFF + r * 8192 + lofs);
        }
    }

    // stage small params
    if (t < 256) ((f32x4*)(smem + B1_OFF))[t] = ((const f32x4*)b1)[t];
    if (t < 128) {
        uint4 p;
        p.x = pk2(b2[0 * 128 + t], b2[1 * 128 + t]);
        p.y = pk2(b2[2 * 128 + t], b2[3 * 128 + t]);
        p.z = pk2(b2[4 * 128 + t], b2[5 * 128 + t]);
        p.w = pk2(b2[6 * 128 + t], b2[7 * 128 + t]);
        *(uint4*)(smem + B2T_OFF + t * 16) = p;
    }
    if (t < 8) ((float*)(smem + AL_OFF))[t] = alpha[t];

    // ---- stage X (fp32->bf16, swizzled) + fp32 gating ----
    {
        const int m = t & 255, half = t >> 8;
        f32x4 plo = {0.f,0.f,0.f,0.f}, phi = {0.f,0.f,0.f,0.f};
        #pragma unroll
        for (int cc = 0; cc < 8; ++cc) {
            const int c0 = half * 64 + cc * 8;
            float v[8];
            #pragma unroll
            for (int j = 0; j < 8; ++j) v[j] = x[xbase + (size_t)(c0 + j) * SPAT + m];
            #pragma unroll
            for (int j = 0; j < 8; ++j) {
                const f32x4 g0 = *(const f32x4*)(gw + (c0 + j) * NE);
                const f32x4 g1 = *(const f32x4*)(gw + (c0 + j) * NE + 4);
                plo += v[j] * g0; phi += v[j] * g1;
            }
            uint4 pkv;
            pkv.x = pk2(v[0], v[1]); pkv.y = pk2(v[2], v[3]);
            pkv.z = pk2(v[4], v[5]); pkv.w = pk2(v[6], v[7]);
            const int g = half * 8 + cc;
            *(uint4*)(smem + XS_OFF + m * 256 + ((g ^ (m & 7)) * 16)) = pkv;
        }
        if (half) {
            *(f32x4*)(smem + PL_OFF + m * 32)      = plo;
            *(f32x4*)(smem + PL_OFF + m * 32 + 16) = phi;
        }
        __syncthreads();
        if (!half) {
            const f32x4 rlo = *(const f32x4*)(smem + PL_OFF + m * 32);
            const f32x4 rhi = *(const f32x4*)(smem + PL_OFF + m * 32 + 16);
            float lg[8];
            #pragma unroll
            for (int e2 = 0; e2 < 4; ++e2) {
                lg[e2]     = plo[e2] + rlo[e2] + gb[e2];
                lg[4 + e2] = phi[e2] + rhi[e2] + gb[4 + e2];
            }
            int i0 = 0; float v0 = lg[0];
            #pragma unroll
            for (int e2 = 1; e2 < 8; ++e2) if (lg[e2] > v0) { v0 = lg[e2]; i0 = e2; }
            int i1 = -1; float v1 = -3.4e38f;
            #pragma unroll
            for (int e2 = 0; e2 < 8; ++e2) if (e2 != i0 && lg[e2] > v1) { v1 = lg[e2]; i1 = e2; }
            const float d  = expf(v1 - v0);
            const float q0 = 1.f / (1.f + d);
            const float q1 = d   / (1.f + d);
            ((unsigned*)(smem + SEL_OFF))[m] = (unsigned)i0 | ((unsigned)i1 << 8);
            ((float*)(smem + Q_OFF))[m * 2]     = q0;
            ((float*)(smem + Q_OFF))[m * 2 + 1] = q1;
            float cb[8];
            #pragma unroll
            for (int e2 = 0; e2 < 8; ++e2)
                cb[e2] = (e2 == i0) ? q0 : ((e2 == i1) ? q1 : 0.f);
            uint4 cw;
            cw.x = pk2(cb[0], cb[1]); cw.y = pk2(cb[2], cb[3]);
            cw.z = pk2(cb[4], cb[5]); cw.w = pk2(cb[6], cb[7]);
            *(uint4*)(smem + CB_OFF + m * 16) = cw;
        }
    }
    __syncthreads();

    const int mg = w >> 2, ng = w & 3, col = lane & 15, kq = lane >> 4;

    int sel[4]; float cp0[4], cp1[4];
    #pragma unroll
    for (int nf = 0; nf < 4; ++nf) {
        const int tk = ng * 64 + nf * 16 + col;
        sel[nf] = ((const unsigned*)(smem + SEL_OFF))[tk];
        cp0[nf] = ((const float*)(smem + Q_OFF))[tk * 2];
        cp1[nf] = ((const float*)(smem + Q_OFF))[tk * 2 + 1];
    }
    uint4 xb[4][4];
    #pragma unroll
    for (int nf = 0; nf < 4; ++nf) {
        const int row = ng * 64 + nf * 16 + col;
        #pragma unroll
        for (int kt = 0; kt < 4; ++kt)
            xb[nf][kt] = *(const uint4*)(smem + XS_OFF + row * 256 + (((kt * 4 + kq) ^ (row & 7)) * 16));
    }
    __syncthreads();   // xb safe (XS becomes H1); expert-0 weights drained (vmcnt0)

    f32x4 acc[4][4] = {};

    for (int e = 0; e < NE; ++e) {
        const float alph = ((const float*)(smem + AL_OFF))[e];
        // -------- GEMM1: h1[o][tok]; bias+PReLU, fold ce; write H1 (XS region) --------
        #pragma unroll
        for (int ml = 0; ml < 4; ++ml) {
            const int mt = mg * 4 + ml;
            const int o  = mt * 16 + col;
            uint4 a1[4];
            #pragma unroll
            for (int kt = 0; kt < 4; ++kt)
                a1[kt] = *(const uint4*)(smem + WA_OFF + o * 256 + (((kt * 4 + kq) ^ (o & 7)) * 16));
            f32x4 h[4] = {};
            #pragma unroll
            for (int kt = 0; kt < 4; ++kt)
                #pragma unroll
                for (int nf = 0; nf < 4; ++nf)
                    h[nf] = __builtin_amdgcn_mfma_f32_16x16x32_bf16(
                        __builtin_bit_cast(bf16x8, a1[kt]),
                        __builtin_bit_cast(bf16x8, xb[nf][kt]), h[nf], 0, 0, 0);
            const f32x4 b1v = *(const f32x4*)(smem + B1_OFF + e * 512 + (mt * 16 + kq * 4) * 4);
            #pragma unroll
            for (int nf = 0; nf < 4; ++nf) {
                const float ce = ((sel[nf] & 255) == e) ? cp0[nf]
                               : ((((sel[nf] >> 8) & 255) == e) ? cp1[nf] : 0.f);
                float hv[4];
                #pragma unroll
                for (int i = 0; i < 4; ++i) {
                    float z = h[nf][i] + b1v[i];
                    z = (z > 0.f) ? z : alph * z;
                    hv[i] = z * ce;
                }
                const int tok = ng * 64 + nf * 16 + col;
                const int o0  = mt * 16 + kq * 4;
                const int g   = o0 >> 3;
                uint2 pw; pw.x = pk2(hv[0], hv[1]); pw.y = pk2(hv[2], hv[3]);
                *(uint2*)(smem + XS_OFF + tok * 256 + ((g ^ (tok & 7)) * 16) + ((o0 & 4) << 1)) = pw;
            }
        }
        __syncthreads();   // B1: H1 visible, WA free, W2[e] landed
        if (e < 7) {       // prefetch W1[e+1]; lands during GEMM2
            const int off = w * 1024 + lane * 16, lofs = w * 1024;
            const unsigned char* src = wimg + (e + 1) * 32768;
            #pragma unroll
            for (int r = 0; r < 4; ++r)
                gload16(src + r * 8192 + off, smem + WA_OFF + r * 8192 + lofs);
        }
        // -------- GEMM2 (transposed): acc[tok][o] += h1^T . W2^T --------
        #pragma unroll
        for (int kt = 0; kt < 4; ++kt) {
            uint4 hb[4], wf[4];
            #pragma unroll
            for (int m2 = 0; m2 < 4; ++m2) {
                const int tok = ng * 64 + m2 * 16 + col;
                hb[m2] = *(const uint4*)(smem + XS_OFF + tok * 256 + (((kt * 4 + kq) ^ (tok & 7)) * 16));
            }
            #pragma unroll
            for (int n2 = 0; n2 < 4; ++n2) {
                const int o2 = mg * 64 + n2 * 16 + col;
                wf[n2] = *(const uint4*)(smem + WB_OFF + o2 * 256 + (((kt * 4 + kq) ^ (o2 & 7)) * 16));
            }
            #pragma unroll
            for (int m2 = 0; m2 < 4; ++m2)
                #pragma unroll
                for (int n2 = 0; n2 < 4; ++n2)
                    acc[m2][n2] = __builtin_amdgcn_mfma_f32_16x16x32_bf16(
                        __builtin_bit_cast(bf16x8, hb[m2]),
                        __builtin_bit_cast(bf16x8, wf[n2]), acc[m2][n2], 0, 0, 0);
        }
        __syncthreads();   // B2: H1 free, WB free, W1[e+1] landed
        if (e < 7) {       // prefetch W2[e+1]; lands during next GEMM1
            const int off = w * 1024 + lane * 16, lofs = w * 1024;
            const unsigned char* src = wimg + 262144 + (e + 1) * 32768;
            #pragma unroll
            for (int r = 0; r < 4; ++r)
                gload16(src + r * 8192 + off, smem + WB_OFF + r * 8192 + lofs);
        }
    }

    // -------- bias-combine as one K=32 MFMA: acc += combine . b2 --------
    {
        const uint4 z4 = {0u, 0u, 0u, 0u};
        uint4 paf[4], pbf[4];
        #pragma unroll
        for (int m2 = 0; m2 < 4; ++m2) {
            const int tok = ng * 64 + m2 * 16 + col;
            paf[m2] = (kq == 0) ? *(const uint4*)(smem + CB_OFF + tok * 16) : z4;
        }
        #pragma unroll
        for (int n2 = 0; n2 < 4; ++n2) {
            const int o2 = mg * 64 + n2 * 16 + col;
            pbf[n2] = (kq == 0) ? *(const uint4*)(smem + B2T_OFF + o2 * 16) : z4;
        }
        #pragma unroll
        for (int m2 = 0; m2 < 4; ++m2)
            #pragma unroll
            for (int n2 = 0; n2 < 4; ++n2)
                acc[m2][n2] = __builtin_amdgcn_mfma_f32_16x16x32_bf16(
                    __builtin_bit_cast(bf16x8, paf[m2]),
                    __builtin_bit_cast(bf16x8, pbf[n2]), acc[m2][n2], 0, 0, 0);
    }

    // -------- epilogue: residual + coalesced dwordx4 stores --------
    #pragma unroll
    for (int m2 = 0; m2 < 4; ++m2) {
        const int tok0 = ng * 64 + m2 * 16 + kq * 4;
        #pragma unroll
        for (int n2 = 0; n2 < 4; ++n2) {
            const int o2 = mg * 64 + n2 * 16 + col;
            const size_t a = xbase + (size_t)o2 * SPAT + tok0;
            const f32x4 xv = *(const f32x4*)(x + a);
            f32x4 r = acc[m2][n2];
            r += xv;
            *(f32x4*)(out + a) = r;
        }
    }
}

extern "C" void kernel_launch(void* const* d_in, const int* in_sizes, int n_in,
                              void* d_out, int out_size, void* d_ws, size_t ws_size,
                              hipStream_t stream) {
    const float* x  = (const float*)d_in[0];
    const float* gw = (const float*)d_in[1];
    const float* gb = (const float*)d_in[2];
    const float* W1 = (const float*)d_in[3];
    const float* b1 = (const float*)d_in[4];
    const float* al = (const float*)d_in[5];
    const float* W2 = (const float*)d_in[6];
    const float* b2 = (const float*)d_in[7];
    (void)in_sizes; (void)n_in; (void)out_size; (void)ws_size;
    unsigned char* wimg = (unsigned char*)d_ws;   // needs 512 KiB
    float* out = (float*)d_out;

    conv_w<<<dim3(128), dim3(256), 0, stream>>>(W1, W2, wimg);
    moe_main<<<dim3(512), dim3(512), 0, stream>>>(x, gw, gb, b1, al, b2, wimg, out);
}